// Round 7
// baseline (55.250 us; speedup 1.0000x reference)
//
#include <hip/hip_runtime.h>

#define HH 256
#define WW 256
#define PLANE (HH * WW)          // 65536
#define CORE 16                  // output rows per strip (16 strips per image)
#define HALO 16                  // temporal halo rows (>= steps per launch)
#define SLAB 48                  // CORE + 2*HALO
#define NW 8                     // waves per block (512 threads)
#define RPW 6                    // slab rows per wave (SLAB / NW)

// Horizontal neighbor exchange on the VALU pipe via gfx9 DPP wave shifts.
// bound_ctrl zero-fill gives the image-border zero-pad for free at lanes 0/63.
__device__ __forceinline__ float dpp_shfl_up1(float x) {   // lane i <- lane i-1; lane 0 <- 0
    return __int_as_float(__builtin_amdgcn_update_dpp(
        0, __float_as_int(x), 0x138 /*wave_shr:1*/, 0xf, 0xf, true));
}
__device__ __forceinline__ float dpp_shfl_dn1(float x) {   // lane i <- lane i+1; lane 63 <- 0
    return __int_as_float(__builtin_amdgcn_update_dpp(
        0, __float_as_int(x), 0x130 /*wave_shl:1*/, 0xf, 0xf, true));
}

// R7 structure: 512 blocks of 512 threads (8 waves) -> TWO independent
// barrier groups per CU. R5/R6 showed per-step cost ~1.5us invariant to
// per-wave work => latency/barrier-bound with 1 block/CU; two co-resident
// blocks let one block's compute fill the other's barrier/LDS bubbles,
// and 8-wave barriers have less skew than 16-wave ones.
// One block = one 48-row slab (16-row core + 16-row halo each side) of one
// image; u, D, rho in registers (6 rows x 4 cols per thread). Vertical
// neighbors via double-buffered LDS boundary rows, ONE barrier per step.
// Trapezoid: wave w runs my_steps = max(0, ls - d_min(w)) steps
// (wave-uniform); stale neighbor rows land only in the reader's don't-care
// region (telescoping exactness argument, same as the verified R4/R5 form).
// Rows at distance d from the core load u only if d <= ls, params if d < ls;
// unloaded rows are 0 with D=rho=0 and stay 0 (= conv zero-pad).
__global__ __launch_bounds__(512, 4)
void rd_tb8_kernel(const float* __restrict__ uin,
                   const float* __restrict__ params,
                   const int* __restrict__ t,
                   float* __restrict__ uout,
                   int base, int k)
{
    __shared__ float4 vt[2][NW][64];   // each wave's top row (dr=0)
    __shared__ float4 vb[2][NW][64];   // each wave's bottom row (dr=RPW-1)

    const int blk   = blockIdx.x;
    const int b     = blk >> 4;          // image index (16 strips per image)
    const int strip = blk & 15;
    const int r0    = strip * CORE;
    const int w     = threadIdx.x >> 6;  // wave = row-group, 0..7
    const int lane  = threadIdx.x & 63;  // lane = col-group (4 cols each)
    const int c0    = lane << 2;

    int ls = t[b] - base;
    ls = ls < 0 ? 0 : (ls > k ? k : ls);

    // wave's closest-row distance from the core slab band [HALO, HALO+CORE-1]
    const int top_gap = HALO - (RPW * w + RPW - 1);
    const int bot_gap = RPW * w - (HALO + CORE - 1);
    int d_min = top_gap > bot_gap ? top_gap : bot_gap;
    if (d_min < 0) d_min = 0;
    int my_steps = ls - d_min;
    if (my_steps < 0) my_steps = 0;

    const int growbase = r0 - HALO + RPW * w;  // global row of this thread's dr=0
    const size_t ubase = (size_t)b * PLANE;
    const size_t pbase = (size_t)b * 2 * PLANE;

    float u[RPW][4], pD[RPW][4], pR[RPW][4];

    #pragma unroll
    for (int dr = 0; dr < RPW; ++dr) {
        const int grow = growbase + dr;
        const bool inimg = (grow >= 0) && (grow < HH);
        int dist = 0;
        if (grow < r0)                 dist = r0 - grow;
        else if (grow > r0 + CORE - 1) dist = grow - (r0 + CORE - 1);
        const bool needU = inimg && (dist <= ls);
        const bool needP = inimg && (dist < ls);   // params only for rows that compute

        if (needU) {
            const float4 uu = *reinterpret_cast<const float4*>(uin + ubase + (size_t)grow * WW + c0);
            u[dr][0] = uu.x; u[dr][1] = uu.y; u[dr][2] = uu.z; u[dr][3] = uu.w;
        } else {
            u[dr][0] = u[dr][1] = u[dr][2] = u[dr][3] = 0.f;
        }
        if (needP) {
            const float4 dd = *reinterpret_cast<const float4*>(params + pbase + (size_t)grow * WW + c0);
            const float4 rr = *reinterpret_cast<const float4*>(params + pbase + PLANE + (size_t)grow * WW + c0);
            pD[dr][0] = dd.x; pD[dr][1] = dd.y; pD[dr][2] = dd.z; pD[dr][3] = dd.w;
            pR[dr][0] = rr.x; pR[dr][1] = rr.y; pR[dr][2] = rr.z; pR[dr][3] = rr.w;
        } else {
            pD[dr][0] = pD[dr][1] = pD[dr][2] = pD[dr][3] = 0.f;
            pR[dr][0] = pR[dr][1] = pR[dr][2] = pR[dr][3] = 0.f;
        }
    }

    if (ls > 0) {
        // publish initial wave-boundary rows into buffer 0 (all waves)
        vt[0][w][lane] = make_float4(u[0][0], u[0][1], u[0][2], u[0][3]);
        vb[0][w][lane] = make_float4(u[RPW-1][0], u[RPW-1][1], u[RPW-1][2], u[RPW-1][3]);

        for (int s = 0; s < ls; ++s) {
            __syncthreads();                 // buf[s&1] now visible to all waves
            if (s < my_steps) {              // wave-uniform trapezoid skip
                const int cur = s & 1;

                float upr[4] = {0.f, 0.f, 0.f, 0.f};
                float dnr[4] = {0.f, 0.f, 0.f, 0.f};
                if (w > 0)      { float4 v = vb[cur][w-1][lane]; upr[0]=v.x; upr[1]=v.y; upr[2]=v.z; upr[3]=v.w; }
                if (w < NW - 1) { float4 v = vt[cur][w+1][lane]; dnr[0]=v.x; dnr[1]=v.y; dnr[2]=v.z; dnr[3]=v.w; }

                float up_old[4];             // old value of row dr-1 (rolling carry)
                #pragma unroll
                for (int dr = 0; dr < RPW; ++dr) {
                    // horizontal neighbors via DPP (VALU pipe, border zero-fill free)
                    const float lf = dpp_shfl_up1(u[dr][3]);
                    const float rt = dpp_shfl_dn1(u[dr][0]);

                    float old[4], un[4];
                    #pragma unroll
                    for (int c = 0; c < 4; ++c) old[c] = u[dr][c];

                    #pragma unroll
                    for (int c = 0; c < 4; ++c) {
                        const float upv = dr ? up_old[c] : upr[c];
                        const float dnv = (dr < RPW - 1) ? u[dr+1][c] : dnr[c];
                        const float lv  = c ? old[c-1] : lf;
                        const float rv  = (c < 3) ? old[c+1] : rt;
                        const float uc  = old[c];
                        const float s4  = (upv + dnv) + (lv + rv);
                        const float lap = fmaf(-4.0f, uc, s4);
                        const float g   = fmaf(-uc, uc, uc);          // uc*(1-uc)
                        const float a   = fmaf(pD[dr][c], lap, uc);
                        const float nv  = fmaf(pR[dr][c], g, a);
                        un[c] = __builtin_amdgcn_fmed3f(nv, 0.0f, 1.0f);
                    }
                    #pragma unroll
                    for (int c = 0; c < 4; ++c) { u[dr][c] = un[c]; up_old[c] = old[c]; }
                }

                const int nxt = cur ^ 1;
                vt[nxt][w][lane] = make_float4(u[0][0], u[0][1], u[0][2], u[0][3]);
                vb[nxt][w][lane] = make_float4(u[RPW-1][0], u[RPW-1][1], u[RPW-1][2], u[RPW-1][3]);
            }
        }
    }

    // write back the 16-row core (per-row predicate; slab rows 16..31)
    #pragma unroll
    for (int dr = 0; dr < RPW; ++dr) {
        const int grow = growbase + dr;
        if (grow >= r0 && grow < r0 + CORE) {
            *reinterpret_cast<float4*>(uout + ubase + (size_t)grow * WW + c0) =
                make_float4(u[dr][0], u[dr][1], u[dr][2], u[dr][3]);
        }
    }
}

extern "C" void kernel_launch(void* const* d_in, const int* in_sizes, int n_in,
                              void* d_out, int out_size, void* d_ws, size_t ws_size,
                              hipStream_t stream) {
    (void)in_sizes; (void)n_in; (void)out_size; (void)ws_size;
    const float* u      = (const float*)d_in[0];
    const float* params = (const float*)d_in[1];
    const int*   t      = (const int*)d_in[2];
    float*       out    = (float*)d_out;
    float*       ws     = (float*)d_ws;

    const dim3 grid(512), block(512);
    // steps [0,16) -> ws, steps [16,31) -> out
    rd_tb8_kernel<<<grid, block, 0, stream>>>(u,  params, t, ws,  0,  16);
    rd_tb8_kernel<<<grid, block, 0, stream>>>(ws, params, t, out, 16, 15);
}